// Round 4
// baseline (296.527 us; speedup 1.0000x reference)
//
#include <hip/hip_runtime.h>
#include <hip/hip_bf16.h>

#define B_  32
#define S_  1024
#define E_  768
#define HD_ 64
#define M_  (B_*S_)   // 32768 rows of x

typedef __attribute__((ext_vector_type(8))) short short8;   // 8 bf16 (4 VGPR)
typedef __attribute__((ext_vector_type(4))) float float4v;  // MFMA acc

__device__ __forceinline__ float bf2f(unsigned short u) {
    union { unsigned int i; float f; } c; c.i = ((unsigned int)u) << 16; return c.f;
}
// fp32 -> bf16 round-to-nearest-even
__device__ __forceinline__ unsigned short f2bf(float x) {
    union { float f; unsigned u; } c; c.f = x;
    unsigned r = (c.u + 0x7FFFu + ((c.u >> 16) & 1u)) >> 16;
    return (unsigned short)r;
}

// load 8 elements as bf16 frag, either straight bf16 or fp32->bf16
__device__ __forceinline__ short8 load_frag(const void* p, bool isb, size_t off) {
    if (isb) {
        return *(const short8*)((const unsigned short*)p + off);
    } else {
        const float* f = (const float*)p + off;
        float4 a = *(const float4*)f, b = *(const float4*)(f + 4);
        short8 r;
        r[0] = (short)f2bf(a.x); r[1] = (short)f2bf(a.y);
        r[2] = (short)f2bf(a.z); r[3] = (short)f2bf(a.w);
        r[4] = (short)f2bf(b.x); r[5] = (short)f2bf(b.y);
        r[6] = (short)f2bf(b.z); r[7] = (short)f2bf(b.w);
        return r;
    }
}

// ---------------------------------------------------------------------------
// dtype sniffer (verified rounds 2-3)
// ---------------------------------------------------------------------------
__global__ void detect_kernel(const unsigned int* __restrict__ xw,
                              unsigned int* __restrict__ flag) {
    __shared__ int cnt;
    if (threadIdx.x == 0) cnt = 0;
    __syncthreads();
    unsigned int w = xw[(size_t)threadIdx.x * 33331];
    unsigned int e = (w >> 8) & 0x7F;
    int hit = (e >= 0x3B && e <= 0x40) ? 1 : 0;
    atomicAdd(&cnt, hit);
    __syncthreads();
    if (threadIdx.x == 0) *flag = (cnt > 128) ? 1u : 0u;
}

// ---------------------------------------------------------------------------
// RoPE tables: theta_ii = 10000^(-ii/16)
// ---------------------------------------------------------------------------
__global__ __launch_bounds__(256) void rope_table_kernel(float* __restrict__ cs_t,
                                                         float* __restrict__ sn_t) {
    int idx = blockIdx.x * 256 + threadIdx.x;   // 0 .. 32767
    int pos = idx >> 5;
    int ii  = idx & 31;
    float theta = exp2f(-(float)ii * 0.8304820237218406f);  // log2(10000)/16
    float fr = (float)pos * theta;
    float sn, cs;
    sincosf(fr, &sn, &cs);
    cs_t[idx] = cs;
    sn_t[idx] = sn;
}

// ---------------------------------------------------------------------------
// QKV projection + RoPE, MFMA 16x16x32 bf16, BARRIER-FREE.
// Grid 1024, block 256 (4 waves). Block: 32 rows; wave w: cols w*48..w*48+47
// (3 n-tiles) x 2 m-tiles. A/B fragments loaded DIRECTLY from global:
//   A[m=l15][k=quad*8+j] = x[(row0+mt*16+l15)*E + k0 + quad*8 ...]
//   B[n=l15][k=quad*8+j] = W [(c&63)+l15 row]
// W is 288 KB total -> L2-resident. No LDS, no __syncthreads.
// ---------------------------------------------------------------------------
__global__ __launch_bounds__(256) void qkv_mfma_kernel(
    const void* __restrict__ x_, const void* __restrict__ Wq_,
    const void* __restrict__ Wk_, const void* __restrict__ Wv_,
    const unsigned int* __restrict__ flag,
    const float* __restrict__ cs_t, const float* __restrict__ sn_t,
    unsigned short* __restrict__ rq, unsigned short* __restrict__ rk,
    unsigned short* __restrict__ vt)
{
    const bool isb = (*flag != 0);
    const int t    = threadIdx.x;
    const int lane = t & 63;
    const int wave = t >> 6;
    const int quad = lane >> 4;
    const int l15  = lane & 15;
    const int row0 = blockIdx.x * 32;

    float4v acc[3][2];
    #pragma unroll
    for (int nt = 0; nt < 3; ++nt)
        #pragma unroll
        for (int mt = 0; mt < 2; ++mt)
            #pragma unroll
            for (int r = 0; r < 4; ++r) acc[nt][mt][r] = 0.f;

    // per-n-tile W source (wave-uniform matrix select, l15 row within)
    const void* bsrc[3];
    int c0v[3];
    #pragma unroll
    for (int nt = 0; nt < 3; ++nt) {
        int c0 = wave * 48 + nt * 16;
        c0v[nt] = c0;
        int region = c0 >> 6;
        bsrc[nt] = (region == 0) ? Wq_ : (region == 1 ? Wk_ : Wv_);
    }

    // base element offsets
    size_t aoff[2], boff[3];
    #pragma unroll
    for (int mt = 0; mt < 2; ++mt)
        aoff[mt] = (size_t)(row0 + mt * 16 + l15) * E_ + quad * 8;
    #pragma unroll
    for (int nt = 0; nt < 3; ++nt)
        boff[nt] = (size_t)((c0v[nt] & 63) + l15) * E_ + quad * 8;

    #pragma unroll 4
    for (int k0 = 0; k0 < E_; k0 += 32) {
        short8 af[2], bf[3];
        #pragma unroll
        for (int mt = 0; mt < 2; ++mt) af[mt] = load_frag(x_, isb, aoff[mt] + k0);
        #pragma unroll
        for (int nt = 0; nt < 3; ++nt) bf[nt] = load_frag(bsrc[nt], isb, boff[nt] + k0);
        #pragma unroll
        for (int nt = 0; nt < 3; ++nt)
            #pragma unroll
            for (int mt = 0; mt < 2; ++mt)
                acc[nt][mt] = __builtin_amdgcn_mfma_f32_16x16x32_bf16(
                    af[mt], bf[nt], acc[nt][mt], 0, 0, 0);
    }

    // Epilogue: C layout col=l15, row=quad*4+r. RoPE on q/k; v transposed.
    const int b      = row0 >> 10;
    const int s_in_b = row0 & (S_ - 1);
    #pragma unroll
    for (int nt = 0; nt < 3; ++nt) {
        int c0 = c0v[nt];
        int region = c0 >> 6;          // 0=q, 1=k, 2=v (wave-uniform)
        int d = (c0 & 63) + l15;
        if (region < 2) {
            unsigned short* dst = (region == 0) ? rq : rk;
            int ii = d >> 1;
            #pragma unroll
            for (int mt = 0; mt < 2; ++mt) {
                #pragma unroll
                for (int r = 0; r < 4; ++r) {
                    int row = row0 + mt * 16 + quad * 4 + r;
                    int pos = row & (S_ - 1);
                    float cs = cs_t[pos * 32 + ii];
                    float sn = sn_t[pos * 32 + ii];
                    float val = acc[nt][mt][r];
                    float partner = __shfl_xor(val, 1);   // pair col d^1 = lane^1
                    float res = (d & 1) ? fmaf(val, cs,  partner * sn)
                                        : fmaf(val, cs, -partner * sn);
                    dst[(size_t)row * HD_ + d] = f2bf(res);
                }
            }
        } else {
            #pragma unroll
            for (int mt = 0; mt < 2; ++mt) {
                int sb = s_in_b + mt * 16 + quad * 4;
                ushort4 pk;
                pk.x = f2bf(acc[nt][mt][0]);
                pk.y = f2bf(acc[nt][mt][1]);
                pk.z = f2bf(acc[nt][mt][2]);
                pk.w = f2bf(acc[nt][mt][3]);
                *(ushort4*)(vt + ((size_t)(b * 64 + d) * S_ + sb)) = pk;
            }
        }
    }
}

// ---------------------------------------------------------------------------
// Flash attention, MFMA 16x16x32 bf16, causal, 2-way in-block K-split.
// Grid (16, 32), block 512 (8 waves). Wave w: qsub = w>>1 (16 q-rows at
// q0 = qt*64 + qsub*16), half h = w&1 processes key-tiles [0,nh) or [nh,qt+1).
// Partials (O raw, m, l) merged through LDS after one barrier.
// ---------------------------------------------------------------------------
__global__ __launch_bounds__(512, 4) void attn_mfma_kernel(
    const unsigned short* __restrict__ rq, const unsigned short* __restrict__ rk,
    const unsigned short* __restrict__ vt, const unsigned int* __restrict__ flag,
    void* __restrict__ out)
{
    __shared__ unsigned short plds[8][16][72];   // per-wave P buffer
    __shared__ float om[8][16][65];              // partial O (padded)
    __shared__ float ml[8][16][2];               // partial m, l

    const bool isb = (*flag != 0);
    const int t    = threadIdx.x;
    const int lane = t & 63;
    const int wave = t >> 6;        // 0..7
    const int quad = lane >> 4;
    const int l15  = lane & 15;
    const int qt   = blockIdx.x;
    const int b    = blockIdx.y;
    const int qsub = wave >> 1;
    const int h    = wave & 1;
    const int q0   = qt * 64 + qsub * 16;
    const float scale = 0.03608439182435161f;   // 768^-0.5

    // Q A-frags (persistent)
    const unsigned short* qp = rq + ((size_t)(b * S_ + q0 + l15)) * HD_ + quad * 8;
    short8 qf0 = *(const short8*)qp;
    short8 qf1 = *(const short8*)(qp + 32);

    const unsigned short* kp = rk + ((size_t)(b * S_ + l15)) * HD_ + quad * 8;
    const unsigned short* vp = vt + ((size_t)(b * 64 + l15)) * S_ + quad * 8;

    float4v o[4];
    float m_[4], l_[4];
    #pragma unroll
    for (int nt = 0; nt < 4; ++nt)
        #pragma unroll
        for (int r = 0; r < 4; ++r) o[nt][r] = 0.f;
    #pragma unroll
    for (int r = 0; r < 4; ++r) { m_[r] = -1e30f; l_[r] = 0.f; }

    const int ntiles = qt + 1;
    const int nh     = (ntiles + 1) >> 1;
    const int kt_beg = h ? nh : 0;
    const int kt_end = h ? ntiles : nh;

    for (int kt = kt_beg; kt < kt_end; ++kt) {
        const int k0 = kt * 64;

        // ---- S = Q K^T ----
        float4v s[4];
        #pragma unroll
        for (int nt = 0; nt < 4; ++nt) {
            #pragma unroll
            for (int r = 0; r < 4; ++r) s[nt][r] = 0.f;
            const unsigned short* kpp = kp + (size_t)(k0 + nt * 16) * HD_;
            short8 kf0 = *(const short8*)kpp;
            short8 kf1 = *(const short8*)(kpp + 32);
            s[nt] = __builtin_amdgcn_mfma_f32_16x16x32_bf16(qf0, kf0, s[nt], 0, 0, 0);
            s[nt] = __builtin_amdgcn_mfma_f32_16x16x32_bf16(qf1, kf1, s[nt], 0, 0, 0);
        }

        float sc[4][4];
        #pragma unroll
        for (int nt = 0; nt < 4; ++nt)
            #pragma unroll
            for (int r = 0; r < 4; ++r) sc[nt][r] = s[nt][r] * scale;

        if (kt == qt) {   // diagonal tile: causal mask
            #pragma unroll
            for (int nt = 0; nt < 4; ++nt) {
                int kg = k0 + nt * 16 + l15;
                #pragma unroll
                for (int r = 0; r < 4; ++r) {
                    int qg = q0 + quad * 4 + r;
                    if (kg > qg) sc[nt][r] = -1e30f;
                }
            }
        }

        // ---- online softmax (reduce over 16 lanes) ----
        float mx[4];
        #pragma unroll
        for (int r = 0; r < 4; ++r)
            mx[r] = fmaxf(fmaxf(sc[0][r], sc[1][r]), fmaxf(sc[2][r], sc[3][r]));
        #pragma unroll
        for (int st = 1; st < 16; st <<= 1)
            #pragma unroll
            for (int r = 0; r < 4; ++r)
                mx[r] = fmaxf(mx[r], __shfl_xor(mx[r], st));

        float al[4];
        #pragma unroll
        for (int r = 0; r < 4; ++r) {
            float mn = fmaxf(m_[r], mx[r]);
            al[r] = __expf(m_[r] - mn);
            m_[r] = mn;
        }

        float pv[4][4];
        float sm[4] = {0.f, 0.f, 0.f, 0.f};
        #pragma unroll
        for (int nt = 0; nt < 4; ++nt)
            #pragma unroll
            for (int r = 0; r < 4; ++r) {
                float p = __expf(sc[nt][r] - m_[r]);
                pv[nt][r] = p;
                sm[r] += p;
            }
        #pragma unroll
        for (int st = 1; st < 16; st <<= 1)
            #pragma unroll
            for (int r = 0; r < 4; ++r)
                sm[r] += __shfl_xor(sm[r], st);
        #pragma unroll
        for (int r = 0; r < 4; ++r) l_[r] = l_[r] * al[r] + sm[r];

        #pragma unroll
        for (int nt = 0; nt < 4; ++nt)
            #pragma unroll
            for (int r = 0; r < 4; ++r) o[nt][r] *= al[r];

        // ---- P: C-layout -> wave-private LDS -> A-layout ----
        #pragma unroll
        for (int nt = 0; nt < 4; ++nt)
            #pragma unroll
            for (int r = 0; r < 4; ++r)
                plds[wave][quad * 4 + r][nt * 16 + l15] = f2bf(pv[nt][r]);
        short8 pf0 = *(const short8*)&plds[wave][l15][quad * 8];
        short8 pf1 = *(const short8*)&plds[wave][l15][32 + quad * 8];

        // ---- O += P V ----
        #pragma unroll
        for (int nt = 0; nt < 4; ++nt) {
            const unsigned short* vpp = vp + (size_t)(nt * 16) * S_ + k0;
            short8 vf0 = *(const short8*)vpp;
            short8 vf1 = *(const short8*)(vpp + 32);
            o[nt] = __builtin_amdgcn_mfma_f32_16x16x32_bf16(pf0, vf0, o[nt], 0, 0, 0);
            o[nt] = __builtin_amdgcn_mfma_f32_16x16x32_bf16(pf1, vf1, o[nt], 0, 0, 0);
        }
    }

    // ---- write partials, merge halves, store ----
    #pragma unroll
    for (int nt = 0; nt < 4; ++nt)
        #pragma unroll
        for (int r = 0; r < 4; ++r)
            om[wave][quad * 4 + r][nt * 16 + l15] = o[nt][r];
    if (l15 == 0) {
        #pragma unroll
        for (int r = 0; r < 4; ++r) {
            ml[wave][quad * 4 + r][0] = m_[r];
            ml[wave][quad * 4 + r][1] = l_[r];
        }
    }
    __syncthreads();

    if (h == 0) {
        float aa[4], ab[4], linv[4];
        #pragma unroll
        for (int r = 0; r < 4; ++r) {
            int row = quad * 4 + r;
            float mb = ml[wave + 1][row][0];
            float lb = ml[wave + 1][row][1];
            float mn = fmaxf(m_[r], mb);
            aa[r] = __expf(m_[r] - mn);
            ab[r] = __expf(mb - mn);
            linv[r] = 1.0f / (l_[r] * aa[r] + lb * ab[r]);
        }
        if (isb) {
            unsigned short* op = (unsigned short*)out;
            #pragma unroll
            for (int nt = 0; nt < 4; ++nt)
                #pragma unroll
                for (int r = 0; r < 4; ++r) {
                    float ob = om[wave + 1][quad * 4 + r][nt * 16 + l15];
                    float val = (o[nt][r] * aa[r] + ob * ab[r]) * linv[r];
                    size_t row = (size_t)b * S_ + q0 + quad * 4 + r;
                    op[row * HD_ + nt * 16 + l15] = f2bf(val);
                }
        } else {
            float* op = (float*)out;
            #pragma unroll
            for (int nt = 0; nt < 4; ++nt)
                #pragma unroll
                for (int r = 0; r < 4; ++r) {
                    float ob = om[wave + 1][quad * 4 + r][nt * 16 + l15];
                    float val = (o[nt][r] * aa[r] + ob * ab[r]) * linv[r];
                    size_t row = (size_t)b * S_ + q0 + quad * 4 + r;
                    op[row * HD_ + nt * 16 + l15] = val;
                }
        }
    }
}

// ---------------------------------------------------------------------------
extern "C" void kernel_launch(void* const* d_in, const int* in_sizes, int n_in,
                              void* d_out, int out_size, void* d_ws, size_t ws_size,
                              hipStream_t stream) {
    const void* x  = d_in[0];
    const void* Wq = d_in[1];
    const void* Wk = d_in[2];
    const void* Wv = d_in[3];

    // ws layout (~12.3 MB; <= 12.9 MB proven available in round 2)
    unsigned int* flag = (unsigned int*)d_ws;
    float* cs_t = (float*)d_ws + 64;
    float* sn_t = cs_t + (size_t)S_ * 32;
    unsigned short* rq = (unsigned short*)(sn_t + (size_t)S_ * 32);
    unsigned short* rk = rq + (size_t)M_ * HD_;
    unsigned short* vt = rk + (size_t)M_ * HD_;   // [B][64][S] transposed V

    hipLaunchKernelGGL(detect_kernel, dim3(1), dim3(256), 0, stream,
                       (const unsigned int*)x, flag);
    hipLaunchKernelGGL(rope_table_kernel, dim3(128), dim3(256), 0, stream,
                       cs_t, sn_t);
    hipLaunchKernelGGL(qkv_mfma_kernel, dim3(M_ / 32), dim3(256), 0, stream,
                       x, Wq, Wk, Wv, flag, cs_t, sn_t, rq, rk, vt);
    hipLaunchKernelGGL(attn_mfma_kernel, dim3(S_ / 64, B_), dim3(512), 0, stream,
                       rq, rk, vt, flag, d_out);
}

// Round 5
// 243.377 us; speedup vs baseline: 1.2184x; 1.2184x over previous
//
#include <hip/hip_runtime.h>
#include <hip/hip_bf16.h>

#define B_  32
#define S_  1024
#define E_  768
#define HD_ 64
#define M_  (B_*S_)   // 32768 rows of x

typedef __attribute__((ext_vector_type(8))) short short8;   // 8 bf16 (4 VGPR)
typedef __attribute__((ext_vector_type(4))) float float4v;  // MFMA acc

__device__ __forceinline__ float bf2f(unsigned short u) {
    union { unsigned int i; float f; } c; c.i = ((unsigned int)u) << 16; return c.f;
}
// fp32 -> bf16 round-to-nearest-even
__device__ __forceinline__ unsigned short f2bf(float x) {
    union { float f; unsigned u; } c; c.f = x;
    unsigned r = (c.u + 0x7FFFu + ((c.u >> 16) & 1u)) >> 16;
    return (unsigned short)r;
}

// async global->LDS, 16B per lane. LDS dest is the WAVE-UNIFORM tile base;
// HW scatters lane i to base + i*16.
__device__ __forceinline__ void gld_lds16(const void* g, void* l) {
    __builtin_amdgcn_global_load_lds(
        (const __attribute__((address_space(1))) unsigned int*)g,
        (__attribute__((address_space(3))) unsigned int*)l,
        16, 0, 0);
}

// ---------------------------------------------------------------------------
// RoPE tables (blocks 0..127) + dtype sniffer (block 128).
// theta_ii = 10000^(-ii/16)
// ---------------------------------------------------------------------------
__global__ __launch_bounds__(256) void setup_kernel(const unsigned int* __restrict__ xw,
                                                    unsigned int* __restrict__ flag,
                                                    float* __restrict__ cs_t,
                                                    float* __restrict__ sn_t) {
    if (blockIdx.x == 128) {   // dtype sniffer (verified rounds 2-4)
        __shared__ int cnt;
        if (threadIdx.x == 0) cnt = 0;
        __syncthreads();
        unsigned int w = xw[(size_t)threadIdx.x * 33331];
        unsigned int e = (w >> 8) & 0x7F;
        int hit = (e >= 0x3B && e <= 0x40) ? 1 : 0;
        atomicAdd(&cnt, hit);
        __syncthreads();
        if (threadIdx.x == 0) *flag = (cnt > 128) ? 1u : 0u;
        return;
    }
    int idx = blockIdx.x * 256 + threadIdx.x;   // 0 .. 32767
    int pos = idx >> 5;
    int ii  = idx & 31;
    float theta = exp2f(-(float)ii * 0.8304820237218406f);  // log2(10000)/16
    float fr = (float)pos * theta;
    float sn, cs;
    sincosf(fr, &sn, &cs);
    cs_t[idx] = cs;
    sn_t[idx] = sn;
}

// ---------------------------------------------------------------------------
// QKV projection + RoPE, MFMA 16x16x32 bf16, global_load_lds staging.
// Grid 1024, block 256 (4 waves). Block: 32 rows x 192 cols.
// LDS: 28 tiles x 1KB, FRAGMENT ORDER (tile base + lane*16B) -> conflict-free
// b128 reads. Tiles 0-3: A(mt,ks); 4-27: B(ct,ks), ct = q0-3,k4-7,v8-11.
// Wave w stages tiles w*7..w*7+6; computes ct = w*3+nt (n cols w*48..).
// ---------------------------------------------------------------------------
__global__ __launch_bounds__(256, 4) void qkv_mfma_kernel(
    const void* __restrict__ x_, const void* __restrict__ Wq_,
    const void* __restrict__ Wk_, const void* __restrict__ Wv_,
    const unsigned int* __restrict__ flag,
    const float* __restrict__ cs_t, const float* __restrict__ sn_t,
    unsigned short* __restrict__ rq, unsigned short* __restrict__ rk,
    unsigned short* __restrict__ vt)
{
    __shared__ __align__(16) unsigned short smem[28 * 512];   // 28 KB

    const bool isb = (*flag != 0);
    const int t    = threadIdx.x;
    const int lane = t & 63;
    const int wave = t >> 6;
    const int quad = lane >> 4;
    const int l15  = lane & 15;
    const int row0 = blockIdx.x * 32;

    // per-wave staging sources (element offsets; add k0 each chunk)
    const unsigned short* gsrc[7];
    const float*          gsrcf[7];
    unsigned short*       ldst[7];
    #pragma unroll
    for (int i = 0; i < 7; ++i) {
        int tid = wave * 7 + i;
        size_t eo; const void* base;
        if (tid < 4) {                 // A tile: mt = tid>>1, ks = tid&1
            int mt = tid >> 1, ks = tid & 1;
            eo = (size_t)(row0 + mt * 16 + l15) * E_ + ks * 32 + quad * 8;
            base = x_;
        } else {                       // B tile: ct = (tid-4)>>1, ks = (tid-4)&1
            int bi = tid - 4, ct = bi >> 1, ks = bi & 1;
            int reg = ct >> 2;
            base = (reg == 0) ? Wq_ : (reg == 1 ? Wk_ : Wv_);
            eo = (size_t)((ct & 3) * 16 + l15) * E_ + ks * 32 + quad * 8;
        }
        gsrc[i]  = (const unsigned short*)base + eo;
        gsrcf[i] = (const float*)base + eo;
        ldst[i]  = smem + (size_t)tid * 512;   // wave-uniform tile base
    }

    float4v acc[3][2];
    #pragma unroll
    for (int nt = 0; nt < 3; ++nt)
        #pragma unroll
        for (int mt = 0; mt < 2; ++mt)
            #pragma unroll
            for (int r = 0; r < 4; ++r) acc[nt][mt][r] = 0.f;

    for (int k0 = 0; k0 < E_; k0 += 64) {
        if (isb) {
            #pragma unroll
            for (int i = 0; i < 7; ++i)
                gld_lds16(gsrc[i] + k0, ldst[i]);
        } else {
            #pragma unroll
            for (int i = 0; i < 7; ++i) {
                const float* f = gsrcf[i] + k0;
                float4 a = *(const float4*)f, bq = *(const float4*)(f + 4);
                uint4 w;
                w.x = f2bf(a.x)  | ((unsigned)f2bf(a.y)  << 16);
                w.y = f2bf(a.z)  | ((unsigned)f2bf(a.w)  << 16);
                w.z = f2bf(bq.x) | ((unsigned)f2bf(bq.y) << 16);
                w.w = f2bf(bq.z) | ((unsigned)f2bf(bq.w) << 16);
                *(uint4*)(ldst[i] + (size_t)lane * 8) = w;
            }
        }
        __syncthreads();

        #pragma unroll
        for (int ks = 0; ks < 2; ++ks) {
            short8 af[2];
            af[0] = *(const short8*)(smem + (size_t)(0 * 2 + ks) * 512 + lane * 8);
            af[1] = *(const short8*)(smem + (size_t)(1 * 2 + ks) * 512 + lane * 8);
            #pragma unroll
            for (int nt = 0; nt < 3; ++nt) {
                int ct = wave * 3 + nt;
                short8 bf = *(const short8*)(smem + (size_t)(4 + ct * 2 + ks) * 512 + lane * 8);
                acc[nt][0] = __builtin_amdgcn_mfma_f32_16x16x32_bf16(af[0], bf, acc[nt][0], 0, 0, 0);
                acc[nt][1] = __builtin_amdgcn_mfma_f32_16x16x32_bf16(af[1], bf, acc[nt][1], 0, 0, 0);
            }
        }
        __syncthreads();
    }

    // Epilogue (verified round 4): C col=l15, row=quad*4+r. RoPE q/k; v transposed.
    const int b      = row0 >> 10;
    const int s_in_b = row0 & (S_ - 1);
    #pragma unroll
    for (int nt = 0; nt < 3; ++nt) {
        int c0 = (wave * 3 + nt) * 16;
        int region = c0 >> 6;          // 0=q, 1=k, 2=v (wave-uniform)
        int d = (c0 & 63) + l15;
        if (region < 2) {
            unsigned short* dst = (region == 0) ? rq : rk;
            int ii = d >> 1;
            #pragma unroll
            for (int mt = 0; mt < 2; ++mt) {
                #pragma unroll
                for (int r = 0; r < 4; ++r) {
                    int row = row0 + mt * 16 + quad * 4 + r;
                    int pos = row & (S_ - 1);
                    float cs = cs_t[pos * 32 + ii];
                    float sn = sn_t[pos * 32 + ii];
                    float val = acc[nt][mt][r];
                    float partner = __shfl_xor(val, 1);   // pair col d^1 = lane^1
                    float res = (d & 1) ? fmaf(val, cs,  partner * sn)
                                        : fmaf(val, cs, -partner * sn);
                    dst[(size_t)row * HD_ + d] = f2bf(res);
                }
            }
        } else {
            #pragma unroll
            for (int mt = 0; mt < 2; ++mt) {
                int sb = s_in_b + mt * 16 + quad * 4;
                ushort4 pk;
                pk.x = f2bf(acc[nt][mt][0]);
                pk.y = f2bf(acc[nt][mt][1]);
                pk.z = f2bf(acc[nt][mt][2]);
                pk.w = f2bf(acc[nt][mt][3]);
                *(ushort4*)(vt + ((size_t)(b * 64 + d) * S_ + sb)) = pk;
            }
        }
    }
}

// ---------------------------------------------------------------------------
// Flash attention, MFMA 16x16x32 bf16, causal.
// Grid (16, 32), block 256 (4 waves, one 16-row q-subtile each).
// KV tiles staged ONCE per block via global_load_lds into fragment-ordered
// LDS, DOUBLE-BUFFERED: stage kt+1 before computing kt -> load latency
// overlaps compute; the next iteration's barrier drains it.
// Tiles per kt: 0-7 = K(nt,ks), 8-15 = V(nt,ks); 4 per wave.
// ---------------------------------------------------------------------------
__global__ __launch_bounds__(256, 2) void attn_mfma_kernel(
    const unsigned short* __restrict__ rq, const unsigned short* __restrict__ rk,
    const unsigned short* __restrict__ vt, const unsigned int* __restrict__ flag,
    void* __restrict__ out)
{
    __shared__ __align__(16) unsigned short kv[2][16 * 512];   // 2 x 16 KB
    __shared__ unsigned short plds[4][16][72];                 // per-wave P buffer

    const bool isb = (*flag != 0);
    const int t    = threadIdx.x;
    const int lane = t & 63;
    const int wave = t >> 6;
    const int quad = lane >> 4;
    const int l15  = lane & 15;
    const int qt   = blockIdx.x;
    const int b    = blockIdx.y;
    const int q0   = qt * 64 + wave * 16;
    const float scale = 0.03608439182435161f;   // 768^-0.5

    // Q A-frags (persistent)
    const unsigned short* qp = rq + ((size_t)(b * S_ + q0 + l15)) * HD_ + quad * 8;
    short8 qf0 = *(const short8*)qp;
    short8 qf1 = *(const short8*)(qp + 32);

    // staging sources for this wave's 4 tiles (element offsets; + kt*smul)
    const unsigned short* sgp[4];
    int smul[4];
    int stid[4];
    #pragma unroll
    for (int i = 0; i < 4; ++i) {
        int tid = wave * 4 + i;
        stid[i] = tid;
        if (tid < 8) {          // K tile: nt = tid>>1, ks = tid&1
            int nt = tid >> 1, ks = tid & 1;
            sgp[i]  = rk + ((size_t)(b * S_ + nt * 16 + l15)) * HD_ + ks * 32 + quad * 8;
            smul[i] = 64 * HD_;                 // advance 64 key-rows per kt
        } else {                // V tile: nt = (tid-8)>>1, ks = (tid-8)&1
            int vid = tid - 8, nt = vid >> 1, ks = vid & 1;
            sgp[i]  = vt + ((size_t)(b * 64 + nt * 16 + l15)) * S_ + ks * 32 + quad * 8;
            smul[i] = 64;                       // advance 64 keys per kt
        }
    }

    float4v o[4];
    float m_[4], l_[4];
    #pragma unroll
    for (int nt = 0; nt < 4; ++nt)
        #pragma unroll
        for (int r = 0; r < 4; ++r) o[nt][r] = 0.f;
    #pragma unroll
    for (int r = 0; r < 4; ++r) { m_[r] = -1e30f; l_[r] = 0.f; }

    // prefetch kt=0 into buf 0
    #pragma unroll
    for (int i = 0; i < 4; ++i)
        gld_lds16(sgp[i], kv[0] + (size_t)stid[i] * 512);

    int buf = 0;
    for (int kt = 0; kt <= qt; ++kt) {
        __syncthreads();   // drains this wave's gld_lds; syncs prior compute
        if (kt < qt) {
            #pragma unroll
            for (int i = 0; i < 4; ++i)
                gld_lds16(sgp[i] + (size_t)(kt + 1) * smul[i],
                          kv[buf ^ 1] + (size_t)stid[i] * 512);
        }
        const unsigned short* kb = kv[buf];
        const int k0 = kt * 64;

        // ---- S = Q K^T ----
        float4v s[4];
        #pragma unroll
        for (int nt = 0; nt < 4; ++nt) {
            #pragma unroll
            for (int r = 0; r < 4; ++r) s[nt][r] = 0.f;
            short8 kf0 = *(const short8*)(kb + (size_t)(nt * 2 + 0) * 512 + lane * 8);
            short8 kf1 = *(const short8*)(kb + (size_t)(nt * 2 + 1) * 512 + lane * 8);
            s[nt] = __builtin_amdgcn_mfma_f32_16x16x32_bf16(qf0, kf0, s[nt], 0, 0, 0);
            s[nt] = __builtin_amdgcn_mfma_f32_16x16x32_bf16(qf1, kf1, s[nt], 0, 0, 0);
        }

        float sc[4][4];
        #pragma unroll
        for (int nt = 0; nt < 4; ++nt)
            #pragma unroll
            for (int r = 0; r < 4; ++r) sc[nt][r] = s[nt][r] * scale;

        if (kt == qt) {   // diagonal tile: causal mask
            #pragma unroll
            for (int nt = 0; nt < 4; ++nt) {
                int kg = k0 + nt * 16 + l15;
                #pragma unroll
                for (int r = 0; r < 4; ++r) {
                    int qg = q0 + quad * 4 + r;
                    if (kg > qg) sc[nt][r] = -1e30f;
                }
            }
        }

        // ---- online softmax (reduce over 16 lanes) ----
        float mx[4];
        #pragma unroll
        for (int r = 0; r < 4; ++r)
            mx[r] = fmaxf(fmaxf(sc[0][r], sc[1][r]), fmaxf(sc[2][r], sc[3][r]));
        #pragma unroll
        for (int st = 1; st < 16; st <<= 1)
            #pragma unroll
            for (int r = 0; r < 4; ++r)
                mx[r] = fmaxf(mx[r], __shfl_xor(mx[r], st));

        float al[4];
        #pragma unroll
        for (int r = 0; r < 4; ++r) {
            float mn = fmaxf(m_[r], mx[r]);
            al[r] = __expf(m_[r] - mn);
            m_[r] = mn;
        }

        float pv[4][4];
        float sm[4] = {0.f, 0.f, 0.f, 0.f};
        #pragma unroll
        for (int nt = 0; nt < 4; ++nt)
            #pragma unroll
            for (int r = 0; r < 4; ++r) {
                float p = __expf(sc[nt][r] - m_[r]);
                pv[nt][r] = p;
                sm[r] += p;
            }
        #pragma unroll
        for (int st = 1; st < 16; st <<= 1)
            #pragma unroll
            for (int r = 0; r < 4; ++r)
                sm[r] += __shfl_xor(sm[r], st);
        #pragma unroll
        for (int r = 0; r < 4; ++r) l_[r] = l_[r] * al[r] + sm[r];

        #pragma unroll
        for (int nt = 0; nt < 4; ++nt)
            #pragma unroll
            for (int r = 0; r < 4; ++r) o[nt][r] *= al[r];

        // ---- P: C-layout -> wave-private LDS -> A-layout ----
        #pragma unroll
        for (int nt = 0; nt < 4; ++nt)
            #pragma unroll
            for (int r = 0; r < 4; ++r)
                plds[wave][quad * 4 + r][nt * 16 + l15] = f2bf(pv[nt][r]);
        short8 pf0 = *(const short8*)&plds[wave][l15][quad * 8];
        short8 pf1 = *(const short8*)&plds[wave][l15][32 + quad * 8];

        // ---- O += P V ----
        #pragma unroll
        for (int nt = 0; nt < 4; ++nt) {
            short8 vf0 = *(const short8*)(kb + (size_t)(8 + nt * 2 + 0) * 512 + lane * 8);
            short8 vf1 = *(const short8*)(kb + (size_t)(8 + nt * 2 + 1) * 512 + lane * 8);
            o[nt] = __builtin_amdgcn_mfma_f32_16x16x32_bf16(pf0, vf0, o[nt], 0, 0, 0);
            o[nt] = __builtin_amdgcn_mfma_f32_16x16x32_bf16(pf1, vf1, o[nt], 0, 0, 0);
        }
        buf ^= 1;
    }

    // ---- epilogue: normalize, store per dtype ----
    float inv[4];
    #pragma unroll
    for (int r = 0; r < 4; ++r) inv[r] = 1.0f / l_[r];
    if (isb) {
        unsigned short* op = (unsigned short*)out;
        #pragma unroll
        for (int nt = 0; nt < 4; ++nt)
            #pragma unroll
            for (int r = 0; r < 4; ++r) {
                size_t row = (size_t)b * S_ + q0 + quad * 4 + r;
                op[row * HD_ + nt * 16 + l15] = f2bf(o[nt][r] * inv[r]);
            }
    } else {
        float* op = (float*)out;
        #pragma unroll
        for (int nt = 0; nt < 4; ++nt)
            #pragma unroll
            for (int r = 0; r < 4; ++r) {
                size_t row = (size_t)b * S_ + q0 + quad * 4 + r;
                op[row * HD_ + nt * 16 + l15] = o[nt][r] * inv[r];
            }
    }
}

// ---------------------------------------------------------------------------
extern "C" void kernel_launch(void* const* d_in, const int* in_sizes, int n_in,
                              void* d_out, int out_size, void* d_ws, size_t ws_size,
                              hipStream_t stream) {
    const void* x  = d_in[0];
    const void* Wq = d_in[1];
    const void* Wk = d_in[2];
    const void* Wv = d_in[3];

    // ws layout (~12.3 MB; <= 12.9 MB proven available)
    unsigned int* flag = (unsigned int*)d_ws;
    float* cs_t = (float*)d_ws + 64;
    float* sn_t = cs_t + (size_t)S_ * 32;
    unsigned short* rq = (unsigned short*)(sn_t + (size_t)S_ * 32);
    unsigned short* rk = rq + (size_t)M_ * HD_;
    unsigned short* vt = rk + (size_t)M_ * HD_;   // [B][64][S] transposed V

    hipLaunchKernelGGL(setup_kernel, dim3(129), dim3(256), 0, stream,
                       (const unsigned int*)x, flag, cs_t, sn_t);
    hipLaunchKernelGGL(qkv_mfma_kernel, dim3(M_ / 32), dim3(256), 0, stream,
                       x, Wq, Wk, Wv, flag, cs_t, sn_t, rq, rk, vt);
    hipLaunchKernelGGL(attn_mfma_kernel, dim3(S_ / 64, B_), dim3(256), 0, stream,
                       rq, rk, vt, flag, d_out);
}

// Round 6
// 221.403 us; speedup vs baseline: 1.3393x; 1.0992x over previous
//
#include <hip/hip_runtime.h>
#include <hip/hip_bf16.h>

#define B_  32
#define S_  1024
#define E_  768
#define HD_ 64
#define M_  (B_*S_)   // 32768 rows of x

typedef __attribute__((ext_vector_type(8))) short short8;   // 8 bf16 (4 VGPR)
typedef __attribute__((ext_vector_type(4))) float float4v;  // MFMA acc

__device__ __forceinline__ float bf2f(unsigned short u) {
    union { unsigned int i; float f; } c; c.i = ((unsigned int)u) << 16; return c.f;
}
// fp32 -> bf16 round-to-nearest-even
__device__ __forceinline__ unsigned short f2bf(float x) {
    union { float f; unsigned u; } c; c.f = x;
    unsigned r = (c.u + 0x7FFFu + ((c.u >> 16) & 1u)) >> 16;
    return (unsigned short)r;
}

// async global->LDS, 16B per lane; LDS dest = wave-uniform tile base.
__device__ __forceinline__ void gld_lds16(const void* g, void* l) {
    __builtin_amdgcn_global_load_lds(
        (const __attribute__((address_space(1))) unsigned int*)g,
        (__attribute__((address_space(3))) unsigned int*)l,
        16, 0, 0);
}

// ---------------------------------------------------------------------------
// RoPE tables (blocks 0..127) + dtype sniffer (block 128).
// ---------------------------------------------------------------------------
__global__ __launch_bounds__(256) void setup_kernel(const unsigned int* __restrict__ xw,
                                                    unsigned int* __restrict__ flag,
                                                    float* __restrict__ cs_t,
                                                    float* __restrict__ sn_t) {
    if (blockIdx.x == 128) {   // dtype sniffer (verified rounds 2-5)
        __shared__ int cnt;
        if (threadIdx.x == 0) cnt = 0;
        __syncthreads();
        unsigned int w = xw[(size_t)threadIdx.x * 33331];
        unsigned int e = (w >> 8) & 0x7F;
        int hit = (e >= 0x3B && e <= 0x40) ? 1 : 0;
        atomicAdd(&cnt, hit);
        __syncthreads();
        if (threadIdx.x == 0) *flag = (cnt > 128) ? 1u : 0u;
        return;
    }
    int idx = blockIdx.x * 256 + threadIdx.x;   // 0 .. 32767
    int pos = idx >> 5;
    int ii  = idx & 31;
    float theta = exp2f(-(float)ii * 0.8304820237218406f);  // log2(10000)/16
    float fr = (float)pos * theta;
    float sn, cs;
    sincosf(fr, &sn, &cs);
    cs_t[idx] = cs;
    sn_t[idx] = sn;
}

// ---------------------------------------------------------------------------
// QKV projection + RoPE, MFMA 16x16x32 bf16, DOUBLE-BUFFERED gld_lds staging.
// Grid 512, block 256 (4 waves). Block: 64 rows x 192 cols.
// Per chunk (BK=64): 32 LDS tiles x 1KB, fragment order (base + lane*16B).
// Tiles 0-7: A(mt,ks) mt=0..3; 8-31: B(ct,ks) ct=0..11 (q0-3,k4-7,v8-11).
// Wave w stages tiles w*8..w*8+7; computes all 4 mt x 3 nt (ct=w*3+nt).
// Prefetch c+1 issued after barrier -> overlaps compute of c; next barrier
// drains it (compute ~1.2k cyc >= HBM latency -> drain hidden).
// ---------------------------------------------------------------------------
__global__ __launch_bounds__(256, 4) void qkv_mfma_kernel(
    const void* __restrict__ x_, const void* __restrict__ Wq_,
    const void* __restrict__ Wk_, const void* __restrict__ Wv_,
    const unsigned int* __restrict__ flag,
    const float* __restrict__ cs_t, const float* __restrict__ sn_t,
    unsigned short* __restrict__ rq, unsigned short* __restrict__ rk,
    unsigned short* __restrict__ vt)
{
    __shared__ __align__(16) unsigned short smem[2][32 * 512];   // 64 KB

    const bool isb = (*flag != 0);
    const int t    = threadIdx.x;
    const int lane = t & 63;
    const int wave = t >> 6;
    const int quad = lane >> 4;
    const int l15  = lane & 15;
    const int row0 = blockIdx.x * 64;

    // staging descriptors: this wave's 8 tiles (element offsets, u32)
    const void* gbase[8];    // wave-uniform -> SGPR
    unsigned    eo[8];       // per-lane
    int         tidv[8];
    #pragma unroll
    for (int i = 0; i < 8; ++i) {
        int tid = wave * 8 + i;
        tidv[i] = tid;
        if (tid < 8) {                 // A tile: mt = tid>>1, ks = tid&1
            int mt = tid >> 1, ks = tid & 1;
            gbase[i] = x_;
            eo[i] = (unsigned)((row0 + mt * 16 + l15) * E_ + ks * 32 + quad * 8);
        } else {                       // B tile: ct = (tid-8)>>1, ks = (tid-8)&1
            int bi = tid - 8, ct = bi >> 1, ks = bi & 1;
            int reg = ct >> 2;
            gbase[i] = (reg == 0) ? Wq_ : (reg == 1 ? Wk_ : Wv_);
            eo[i] = (unsigned)(((ct & 3) * 16 + l15) * E_ + ks * 32 + quad * 8);
        }
    }

    float4v acc[3][4];
    #pragma unroll
    for (int nt = 0; nt < 3; ++nt)
        #pragma unroll
        for (int mt = 0; mt < 4; ++mt)
            #pragma unroll
            for (int r = 0; r < 4; ++r) acc[nt][mt][r] = 0.f;

    // ---- stage helper (macro-style lambda) ----
    auto stage = [&](int k0, int bsel) {
        if (isb) {
            #pragma unroll
            for (int i = 0; i < 8; ++i)
                gld_lds16((const unsigned short*)gbase[i] + eo[i] + k0,
                          &smem[bsel][(size_t)tidv[i] * 512]);
        } else {
            #pragma unroll
            for (int i = 0; i < 8; ++i) {
                const float* f = (const float*)gbase[i] + eo[i] + k0;
                float4 a = *(const float4*)f, bq = *(const float4*)(f + 4);
                uint4 w;
                w.x = f2bf(a.x)  | ((unsigned)f2bf(a.y)  << 16);
                w.y = f2bf(a.z)  | ((unsigned)f2bf(a.w)  << 16);
                w.z = f2bf(bq.x) | ((unsigned)f2bf(bq.y) << 16);
                w.w = f2bf(bq.z) | ((unsigned)f2bf(bq.w) << 16);
                *(uint4*)(&smem[bsel][(size_t)tidv[i] * 512] + (size_t)lane * 8) = w;
            }
        }
    };

    stage(0, 0);   // prefetch chunk 0
    int buf = 0;
    for (int c = 0; c < 12; ++c) {
        __syncthreads();                       // drains prefetch of chunk c
        if (c < 11) stage((c + 1) * 64, buf ^ 1);
        const unsigned short* sb = smem[buf];
        #pragma unroll
        for (int ks = 0; ks < 2; ++ks) {
            short8 af[4];
            #pragma unroll
            for (int mt = 0; mt < 4; ++mt)
                af[mt] = *(const short8*)(sb + (size_t)(mt * 2 + ks) * 512 + lane * 8);
            #pragma unroll
            for (int nt = 0; nt < 3; ++nt) {
                int ct = wave * 3 + nt;
                short8 bf = *(const short8*)(sb + (size_t)(8 + ct * 2 + ks) * 512 + lane * 8);
                #pragma unroll
                for (int mt = 0; mt < 4; ++mt)
                    acc[nt][mt] = __builtin_amdgcn_mfma_f32_16x16x32_bf16(
                        af[mt], bf, acc[nt][mt], 0, 0, 0);
            }
        }
        buf ^= 1;
    }

    // Epilogue (verified rounds 4-5): C col=l15, row=quad*4+r. RoPE q/k; v transposed.
    const int b      = row0 >> 10;
    const int s_in_b = row0 & (S_ - 1);
    #pragma unroll
    for (int nt = 0; nt < 3; ++nt) {
        int c0 = (wave * 3 + nt) * 16;
        int region = c0 >> 6;          // 0=q, 1=k, 2=v (wave-uniform)
        int d = (c0 & 63) + l15;
        if (region < 2) {
            unsigned short* dst = (region == 0) ? rq : rk;
            int ii = d >> 1;
            #pragma unroll
            for (int mt = 0; mt < 4; ++mt) {
                #pragma unroll
                for (int r = 0; r < 4; ++r) {
                    int row = row0 + mt * 16 + quad * 4 + r;
                    int pos = row & (S_ - 1);
                    float cs = cs_t[pos * 32 + ii];
                    float sn = sn_t[pos * 32 + ii];
                    float val = acc[nt][mt][r];
                    float partner = __shfl_xor(val, 1);   // pair col d^1 = lane^1
                    float res = (d & 1) ? fmaf(val, cs,  partner * sn)
                                        : fmaf(val, cs, -partner * sn);
                    dst[(size_t)row * HD_ + d] = f2bf(res);
                }
            }
        } else {
            #pragma unroll
            for (int mt = 0; mt < 4; ++mt) {
                int sb2 = s_in_b + mt * 16 + quad * 4;
                ushort4 pk;
                pk.x = f2bf(acc[nt][mt][0]);
                pk.y = f2bf(acc[nt][mt][1]);
                pk.z = f2bf(acc[nt][mt][2]);
                pk.w = f2bf(acc[nt][mt][3]);
                *(ushort4*)(vt + ((size_t)(b * 64 + d) * S_ + sb2)) = pk;
            }
        }
    }
}

// ---------------------------------------------------------------------------
// Flash attention, MFMA 16x16x32 bf16, causal, TWO key-tiles per iteration,
// double-buffered gld_lds staging.
// Grid (16, 32), block 256 (4 waves, 16 q-rows each).
// Per iter i: key-tiles 2i and min(2i+1, qt) (dup tail fully masked via
// logical kg). Buffer: 32 tiles x 1KB: K slot0 0-7, K slot1 8-15,
// V slot0 16-23, V slot1 24-31 (tile = slot*8 + nt*2 + ks). 8 per wave.
// ---------------------------------------------------------------------------
__global__ __launch_bounds__(256, 2) void attn_mfma_kernel(
    const unsigned short* __restrict__ rq, const unsigned short* __restrict__ rk,
    const unsigned short* __restrict__ vt, const unsigned int* __restrict__ flag,
    void* __restrict__ out)
{
    __shared__ __align__(16) unsigned short kv[2][32 * 512];   // 2 x 32 KB
    __shared__ unsigned short plds[4][16][72];                 // per-wave P buffer

    const bool isb = (*flag != 0);
    const int t    = threadIdx.x;
    const int lane = t & 63;
    const int wave = t >> 6;
    const int quad = lane >> 4;
    const int l15  = lane & 15;
    const int qt   = blockIdx.x;
    const int b    = blockIdx.y;
    const int q0   = qt * 64 + wave * 16;
    const float scale = 0.03608439182435161f;   // 768^-0.5

    // Q A-frags (persistent)
    const unsigned short* qp = rq + ((size_t)(b * S_ + q0 + l15)) * HD_ + quad * 8;
    short8 qf0 = *(const short8*)qp;
    short8 qf1 = *(const short8*)(qp + 32);

    // staging descriptors: this wave's 8 tiles
    const unsigned short* sbase[8];
    unsigned eo[8];
    int      slotv[8], tidv[8], stride[8];
    #pragma unroll
    for (int i = 0; i < 8; ++i) {
        int tid = wave * 8 + i;
        tidv[i] = tid;
        int isV  = tid >> 4;             // 0=K, 1=V
        int rem  = tid & 15;
        int slot = rem >> 3;
        int wi   = rem & 7;
        int nt   = wi >> 1, ks = wi & 1;
        slotv[i] = slot;
        if (!isV) {
            sbase[i]  = rk;
            eo[i]     = (unsigned)((b * S_ + nt * 16 + l15) * HD_ + ks * 32 + quad * 8);
            stride[i] = 64 * HD_;
        } else {
            sbase[i]  = vt;
            eo[i]     = (unsigned)((b * 64 + nt * 16 + l15) * S_ + ks * 32 + quad * 8);
            stride[i] = 64;
        }
    }

    float4v o[4];
    float m_[4], l_[4];
    #pragma unroll
    for (int nt = 0; nt < 4; ++nt)
        #pragma unroll
        for (int r = 0; r < 4; ++r) o[nt][r] = 0.f;
    #pragma unroll
    for (int r = 0; r < 4; ++r) { m_[r] = -1e30f; l_[r] = 0.f; }

    const int nIter = (qt + 2) >> 1;

    auto stage = [&](int it, int bsel) {
        int ta  = 2 * it;
        int tb  = min(ta + 1, qt);
        #pragma unroll
        for (int i = 0; i < 8; ++i) {
            int kt = slotv[i] ? tb : ta;
            gld_lds16(sbase[i] + eo[i] + (size_t)kt * stride[i],
                      &kv[bsel][(size_t)tidv[i] * 512]);
        }
    };

    stage(0, 0);
    int buf = 0;
    for (int i = 0; i < nIter; ++i) {
        __syncthreads();
        if (i + 1 < nIter) stage(i + 1, buf ^ 1);
        const unsigned short* kb = kv[buf];

        // ---- S = Q K^T for both slots ----
        float sc[2][4][4];
        #pragma unroll
        for (int slot = 0; slot < 2; ++slot) {
            #pragma unroll
            for (int nt = 0; nt < 4; ++nt) {
                float4v s;
                #pragma unroll
                for (int r = 0; r < 4; ++r) s[r] = 0.f;
                short8 kf0 = *(const short8*)(kb + (size_t)(slot * 8 + nt * 2 + 0) * 512 + lane * 8);
                short8 kf1 = *(const short8*)(kb + (size_t)(slot * 8 + nt * 2 + 1) * 512 + lane * 8);
                s = __builtin_amdgcn_mfma_f32_16x16x32_bf16(qf0, kf0, s, 0, 0, 0);
                s = __builtin_amdgcn_mfma_f32_16x16x32_bf16(qf1, kf1, s, 0, 0, 0);
                #pragma unroll
                for (int r = 0; r < 4; ++r) sc[slot][nt][r] = s[r] * scale;
            }
        }

        // ---- causal mask (wave-uniform trigger near diagonal) ----
        if (2 * i + 1 >= qt) {
            #pragma unroll
            for (int slot = 0; slot < 2; ++slot) {
                int ktl = 2 * i + slot;     // LOGICAL tile (dup tail -> all masked)
                #pragma unroll
                for (int nt = 0; nt < 4; ++nt) {
                    int kg = ktl * 64 + nt * 16 + l15;
                    #pragma unroll
                    for (int r = 0; r < 4; ++r) {
                        int qg = q0 + quad * 4 + r;
                        if (kg > qg) sc[slot][nt][r] = -1e30f;
                    }
                }
            }
        }

        // ---- online softmax over 128 keys (16-lane reduce) ----
        float mx[4];
        #pragma unroll
        for (int r = 0; r < 4; ++r) {
            float a0 = fmaxf(fmaxf(sc[0][0][r], sc[0][1][r]), fmaxf(sc[0][2][r], sc[0][3][r]));
            float a1 = fmaxf(fmaxf(sc[1][0][r], sc[1][1][r]), fmaxf(sc[1][2][r], sc[1][3][r]));
            mx[r] = fmaxf(a0, a1);
        }
        #pragma unroll
        for (int st = 1; st < 16; st <<= 1)
            #pragma unroll
            for (int r = 0; r < 4; ++r)
                mx[r] = fmaxf(mx[r], __shfl_xor(mx[r], st));

        float al[4];
        #pragma unroll
        for (int r = 0; r < 4; ++r) {
            float mn = fmaxf(m_[r], mx[r]);
            al[r] = __expf(m_[r] - mn);
            m_[r] = mn;
        }

        float sm[4] = {0.f, 0.f, 0.f, 0.f};
        #pragma unroll
        for (int slot = 0; slot < 2; ++slot)
            #pragma unroll
            for (int nt = 0; nt < 4; ++nt)
                #pragma unroll
                for (int r = 0; r < 4; ++r) {
                    float p = __expf(sc[slot][nt][r] - m_[r]);
                    sc[slot][nt][r] = p;
                    sm[r] += p;
                }
        #pragma unroll
        for (int st = 1; st < 16; st <<= 1)
            #pragma unroll
            for (int r = 0; r < 4; ++r)
                sm[r] += __shfl_xor(sm[r], st);
        #pragma unroll
        for (int r = 0; r < 4; ++r) l_[r] = l_[r] * al[r] + sm[r];

        #pragma unroll
        for (int nt = 0; nt < 4; ++nt)
            #pragma unroll
            for (int r = 0; r < 4; ++r) o[nt][r] *= al[r];

        // ---- per slot: P -> LDS -> A-frag; O += P V ----
        #pragma unroll
        for (int slot = 0; slot < 2; ++slot) {
            #pragma unroll
            for (int nt = 0; nt < 4; ++nt)
                #pragma unroll
                for (int r = 0; r < 4; ++r)
                    plds[wave][quad * 4 + r][nt * 16 + l15] = f2bf(sc[slot][nt][r]);
            short8 pf0 = *(const short8*)&plds[wave][l15][quad * 8];
            short8 pf1 = *(const short8*)&plds[wave][l15][32 + quad * 8];
            #pragma unroll
            for (int nt = 0; nt < 4; ++nt) {
                short8 vf0 = *(const short8*)(kb + (size_t)(16 + slot * 8 + nt * 2 + 0) * 512 + lane * 8);
                short8 vf1 = *(const short8*)(kb + (size_t)(16 + slot * 8 + nt * 2 + 1) * 512 + lane * 8);
                o[nt] = __builtin_amdgcn_mfma_f32_16x16x32_bf16(pf0, vf0, o[nt], 0, 0, 0);
                o[nt] = __builtin_amdgcn_mfma_f32_16x16x32_bf16(pf1, vf1, o[nt], 0, 0, 0);
            }
        }
        buf ^= 1;
    }

    // ---- epilogue: normalize, store per dtype ----
    float inv[4];
    #pragma unroll
    for (int r = 0; r < 4; ++r) inv[r] = 1.0f / l_[r];
    if (isb) {
        unsigned short* op = (unsigned short*)out;
        #pragma unroll
        for (int nt = 0; nt < 4; ++nt)
            #pragma unroll
            for (int r = 0; r < 4; ++r) {
                size_t row = (size_t)b * S_ + q0 + quad * 4 + r;
                op[row * HD_ + nt * 16 + l15] = f2bf(o[nt][r] * inv[r]);
            }
    } else {
        float* op = (float*)out;
        #pragma unroll
        for (int nt = 0; nt < 4; ++nt)
            #pragma unroll
            for (int r = 0; r < 4; ++r) {
                size_t row = (size_t)b * S_ + q0 + quad * 4 + r;
                op[row * HD_ + nt * 16 + l15] = o[nt][r] * inv[r];
            }
    }
}

// ---------------------------------------------------------------------------
extern "C" void kernel_launch(void* const* d_in, const int* in_sizes, int n_in,
                              void* d_out, int out_size, void* d_ws, size_t ws_size,
                              hipStream_t stream) {
    const void* x  = d_in[0];
    const void* Wq = d_in[1];
    const void* Wk = d_in[2];
    const void* Wv = d_in[3];

    // ws layout (~12.3 MB; proven available)
    unsigned int* flag = (unsigned int*)d_ws;
    float* cs_t = (float*)d_ws + 64;
    float* sn_t = cs_t + (size_t)S_ * 32;
    unsigned short* rq = (unsigned short*)(sn_t + (size_t)S_ * 32);
    unsigned short* rk = rq + (size_t)M_ * HD_;
    unsigned short* vt = rk + (size_t)M_ * HD_;   // [B][64][S] transposed V

    hipLaunchKernelGGL(setup_kernel, dim3(129), dim3(256), 0, stream,
                       (const unsigned int*)x, flag, cs_t, sn_t);
    hipLaunchKernelGGL(qkv_mfma_kernel, dim3(M_ / 64), dim3(256), 0, stream,
                       x, Wq, Wk, Wv, flag, cs_t, sn_t, rq, rk, vt);
    hipLaunchKernelGGL(attn_mfma_kernel, dim3(S_ / 64, B_), dim3(256), 0, stream,
                       rq, rk, vt, flag, d_out);
}